// Round 5
// baseline (263.983 us; speedup 1.0000x reference)
//
#include <hip/hip_runtime.h>
#include <math.h>

#define H_DIM 256
#define HEADS 4
#define HD 64
#define TOPK 15
#define NSLOPE 0.2
#define EDGE_CAP_MAX 128
#define CAND_CAP 256

// prep1: 16 blocks. All blocks zero cnt (16 KB); blocks 0..7 also compute wa
// for (head = b>>1, side = b&1).
__global__ __launch_bounds__(256) void prep1_kernel(const float* __restrict__ W,
                                                    const float* __restrict__ att,
                                                    double* __restrict__ wa_dst,
                                                    double* __restrict__ wa_src,
                                                    int* __restrict__ cnt) {
    const int b = blockIdx.x;
    cnt[b * 256 + threadIdx.x] = 0;
    if (b < 2 * HEADS) {
        const int k = threadIdx.x;
        const int h = b >> 1;
        const int side = b & 1;
        double a = 0.0;
        for (int d = 0; d < HD; ++d)
            a += (double)W[(h * HD + d) * H_DIM + k] * (double)att[h * 2 * HD + side * HD + d];
        (side ? wa_src : wa_dst)[h * H_DIM + k] = a;
    }
}

// prep2: fused independent stages, partitioned by blockIdx:
//   [0, 1024)            s-compute: one wave per row (4 rows/block)
//   [1024, 1024+nb)      edge-table build (thread per edge)
//   [1024+nb, +512)      mask pre-pack: packed[i*256+t] bit k = sector(i,t+256k)&&active(t+256k)
__global__ __launch_bounds__(256) void prep2_kernel(
    const float* __restrict__ emb, const double* __restrict__ wa_dst,
    const double* __restrict__ wa_src, double* __restrict__ s_dst,
    double* __restrict__ s_src, const int* __restrict__ eidx,
    const float* __restrict__ ew, int* __restrict__ cnt, int* __restrict__ col_t,
    int* __restrict__ eid_t, float* __restrict__ w_t,
    const int* __restrict__ sector_mask, const int* __restrict__ active,
    unsigned short* __restrict__ packed, int N, int E, int cap, int nb) {
    const int b = blockIdx.x;
    const int tid = threadIdx.x;

    if (b < 1024) {
        // ---- s-compute ----
        const int lane = tid & 63;
        const int wid = tid >> 6;
        const int i = b * 4 + wid;
        double e[4];
#pragma unroll
        for (int m = 0; m < 4; ++m) e[m] = (double)emb[(size_t)i * H_DIM + lane + 64 * m];
        double acc[8];
#pragma unroll
        for (int c = 0; c < 8; ++c) {
            const double* wa = (c & 1) ? wa_src : wa_dst;
            const int h = c >> 1;
            double a = 0.0;
#pragma unroll
            for (int m = 0; m < 4; ++m) a += e[m] * wa[h * H_DIM + lane + 64 * m];
            acc[c] = a;
        }
#pragma unroll
        for (int m = 1; m < 64; m <<= 1) {
#pragma unroll
            for (int c = 0; c < 8; ++c) acc[c] += __shfl_xor(acc[c], m, 64);
        }
        if (lane == 0) {
#pragma unroll
            for (int c = 0; c < 8; ++c) {
                double* dst = (c & 1) ? s_src : s_dst;
                dst[i * HEADS + (c >> 1)] = acc[c];
            }
        }
    } else if (b < 1024 + nb) {
        // ---- edge-table build (slot order nondeterministic; dedup is by max
        // edge id, which is order-independent) ----
        const int e = (b - 1024) * 256 + tid;
        if (e < E) {
            const int r = eidx[e];
            const int c = eidx[E + e];
            const int s = atomicAdd(&cnt[r], 1);
            if (s < cap) {
                col_t[r * cap + s] = c;
                eid_t[r * cap + s] = e;
                w_t[r * cap + s] = ew[e];
            }
        }
    } else {
        // ---- mask pre-pack: 8 rows per block ----
        const int pb = b - 1024 - nb;
#pragma unroll
        for (int rr = 0; rr < 8; ++rr) {
            const int r = pb * 8 + rr;
            const int* mrow = sector_mask + (size_t)r * N;
            unsigned int v = 0;
#pragma unroll
            for (int k = 0; k < 16; ++k) {
                const int j = tid + (k << 8);
                const unsigned bit = (mrow[j] != 0) && (active[j] != 0);
                v |= bit << k;
            }
            packed[r * 256 + tid] = (unsigned short)v;
        }
    }
}

#define FOR16(OP) OP(0) OP(1) OP(2) OP(3) OP(4) OP(5) OP(6) OP(7) \
                  OP(8) OP(9) OP(10) OP(11) OP(12) OP(13) OP(14) OP(15)

// One block per row. 16 fp64 scores in named registers (thread owns columns
// j = tid + 256k). Selection: fp32 keys -> per-wave ballot binary-search
// threshold -> candidate filter -> exact fp64 rank-by-counting.
__global__ __launch_bounds__(256) void main_kernel(
    const double* __restrict__ s_dst, const double* __restrict__ s_src,
    const unsigned short* __restrict__ packed, const int* __restrict__ active,
    const float* __restrict__ lam_p, const int* __restrict__ cnt,
    const int* __restrict__ col_t, const int* __restrict__ eid_t,
    const float* __restrict__ w_t, float* __restrict__ out, int N, int cap) {
    const int i = blockIdx.x;
    const int tid = threadIdx.x;
    const int lane = tid & 63;
    const int wid = tid >> 6;

    __shared__ int ec[EDGE_CAP_MAX];
    __shared__ int ee[EDGE_CAP_MAX];
    __shared__ float ewl[EDGE_CAP_MAX];
    __shared__ int wcol[EDGE_CAP_MAX];
    __shared__ double wadd[EDGE_CAP_MAX];
    __shared__ unsigned int wth[4];
    __shared__ double cand_v[CAND_CAP];
    __shared__ int cand_i[CAND_CAP];
    __shared__ int cand_cnt, wcnt;
    __shared__ double sorted_v[TOPK];
    __shared__ int sorted_i[TOPK];
    __shared__ double exps[TOPK];

    if (tid == 0) { cand_cnt = 0; wcnt = 0; }

    // Stage this row's edge slice into LDS
    int deg = cnt[i];
    if (deg > cap) deg = cap;
    for (int p = tid; p < deg; p += 256) {
        ec[p] = col_t[i * cap + p];
        ee[p] = eid_t[i * cap + p];
        ewl[p] = w_t[i * cap + p];
    }

    const double sd0 = s_dst[i * 4 + 0];
    const double sd1 = s_dst[i * 4 + 1];
    const double sd2 = s_dst[i * 4 + 2];
    const double sd3 = s_dst[i * 4 + 3];
    const bool ai = (active[i] != 0);
    const double lam = (double)lam_p[0];
    const double4* __restrict__ s_src4 = (const double4*)s_src;
    const unsigned int pm = ai ? (unsigned int)packed[i * 256 + tid] : 0u;

    // Phase 1: scores into 16 named fp64 registers
    double v0, v1, v2, v3, v4, v5, v6, v7, v8, v9, v10, v11, v12, v13, v14, v15;
#define INIT_SLOT(K) { \
    const bool m = (pm >> K) & 1u; \
    const double4 sv = s_src4[tid + (K << 8)]; \
    double x0 = sd0 + sv.x, x1 = sd1 + sv.y, x2 = sd2 + sv.z, x3 = sd3 + sv.w; \
    x0 = (x0 < 0.0) ? NSLOPE * x0 : x0; \
    x1 = (x1 < 0.0) ? NSLOPE * x1 : x1; \
    x2 = (x2 < 0.0) ? NSLOPE * x2 : x2; \
    x3 = (x3 < 0.0) ? NSLOPE * x3 : x3; \
    v##K = m ? (0.25 * (x0 + x1 + x2 + x3)) : -INFINITY; }
    FOR16(INIT_SLOT)
#undef INIT_SLOT

    __syncthreads();  // edges + counters visible

    // Phase 2a: parallel dedup (last-write-wins by edge id), thread-per-edge
    if (tid < deg) {
        const int c = ec[tid];
        const int eid = ee[tid];
        bool win = true;
        for (int q = 0; q < deg; ++q)
            if (ec[q] == c && ee[q] > eid) win = false;
        if (win) {
            int p = atomicAdd(&wcnt, 1);
            wcol[p] = c;
            wadd[p] = lam * (double)ewl[tid];
        }
    }
    __syncthreads();

    // Phase 2b: owners apply winner adds (-inf + add stays -inf)
    const int nw = wcnt;
    for (int w = 0; w < nw; ++w) {
        const int c = wcol[w];
        if ((c & 255) == tid) {
            const double add = wadd[w];
            const int kk = c >> 8;
#define ADD_SLOT(K) if (kk == K) v##K += add;
            FOR16(ADD_SLOT)
#undef ADD_SLOT
        }
    }

    // Phase 3a: fp32 monotone keys + per-thread local max
    unsigned int k0, k1, k2, k3, k4, k5, k6, k7, k8, k9, k10, k11, k12, k13, k14, k15;
#define KEY_SLOT(K) { const float f = (float)v##K; const unsigned u = __float_as_uint(f); \
    k##K = u ^ ((unsigned)((int)u >> 31) | 0x80000000u); }
    FOR16(KEY_SLOT)
#undef KEY_SLOT
    unsigned int lmax = k0;
#define LMAX(K) if (k##K > lmax) lmax = k##K;
    FOR16(LMAX)
#undef LMAX

    // Phase 3b: per-wave 15th-largest lane-max via ballot binary search
    // (valid lower bound on the row's true 15th value)
    unsigned int th = 0;
    for (int b = 31; b >= 0; --b) {
        const unsigned int trial = th | (1u << b);
        unsigned long long m = __ballot(lmax >= trial);
        if (__popcll(m) >= TOPK) th = trial;
    }
    if (lane == 0) wth[wid] = th;
    __syncthreads();
    th = wth[0];
    if (wth[1] > th) th = wth[1];
    if (wth[2] > th) th = wth[2];
    if (wth[3] > th) th = wth[3];

    // Phase 3c: candidate filter (superset of true top-15 by monotonicity)
#define FILT(K) if (k##K >= th) { int p = atomicAdd(&cand_cnt, 1); \
    if (p < CAND_CAP) { cand_v[p] = v##K; cand_i[p] = tid + (K << 8); } }
    FOR16(FILT)
#undef FILT
    __syncthreads();

    // Phase 4: exact fp64 rank-by-counting among C candidates (unique ranks)
    int C = cand_cnt;
    if (C > CAND_CAP) C = CAND_CAP;
    if (tid < C) {
        const double mv = cand_v[tid];
        const int mi = cand_i[tid];
        int rank = 0;
        for (int q = 0; q < C; ++q) {
            const double qv = cand_v[q];
            const int qi = cand_i[q];
            rank += ((qv > mv) || (qv == mv && qi < mi)) ? 1 : 0;
        }
        if (rank < TOPK) { sorted_v[rank] = mv; sorted_i[rank] = mi; }
    }
    __syncthreads();

    // Phase 5: softmax + store
    if (tid < TOPK) exps[tid] = exp(sorted_v[tid] - sorted_v[0]);
    __syncthreads();
    if (tid < TOPK) {
        double s = 0.0;
        for (int t = 0; t < TOPK; ++t) s += exps[t];
        const int NK = N * TOPK;
        const int base = i * TOPK + tid;
        out[base] = (float)sorted_i[tid];      // edge_index row 0: topk column idx
        out[NK + base] = (float)i;             // edge_index row 1: source row
        out[2 * NK + base] = (float)(exps[tid] / s);  // edge_weight (softmax)
    }
}

extern "C" void kernel_launch(void* const* d_in, const int* in_sizes, int n_in,
                              void* d_out, int out_size, void* d_ws, size_t ws_size,
                              hipStream_t stream) {
    const float* emb    = (const float*)d_in[0];
    const float* W      = (const float*)d_in[1];
    const float* att    = (const float*)d_in[2];
    const float* lam    = (const float*)d_in[3];
    const int*   sector = (const int*)d_in[4];
    const int*   active = (const int*)d_in[5];
    const int*   eidx   = (const int*)d_in[6];
    const float* ew     = (const float*)d_in[7];
    float* out = (float*)d_out;

    const int N = in_sizes[5];      // 4096
    const int E = in_sizes[6] / 2;  // 131072

    // workspace layout
    double* wa_dst = (double*)d_ws;                       // 1024 dbl
    double* wa_src = wa_dst + HEADS * H_DIM;              // 1024 dbl
    double* s_dst  = wa_src + HEADS * H_DIM;              // N*4 dbl
    double* s_src  = s_dst + (size_t)N * HEADS;           // N*4 dbl
    int* cnt       = (int*)(s_src + (size_t)N * HEADS);   // N int
    unsigned short* packed = (unsigned short*)(cnt + N);  // N*256 ushort (2 MB)
    int* col_t     = (int*)(packed + (size_t)N * 256);

    size_t used = (size_t)(2 * HEADS * H_DIM + 2 * (size_t)N * HEADS) * 8
                  + (size_t)N * 4 + (size_t)N * 512 + 256;
    size_t rem = (ws_size > used) ? (ws_size - used) : 0;
    int cap = (int)(rem / ((size_t)N * 12));
    if (cap > EDGE_CAP_MAX) cap = EDGE_CAP_MAX;
    if (cap < 16) cap = 16;

    int* eid_t = col_t + (size_t)N * cap;
    float* w_t = (float*)(eid_t + (size_t)N * cap);

    const int nb = (E + 255) / 256;  // build blocks (512)

    prep1_kernel<<<16, 256, 0, stream>>>(W, att, wa_dst, wa_src, cnt);
    prep2_kernel<<<1024 + nb + 512, 256, 0, stream>>>(emb, wa_dst, wa_src, s_dst, s_src,
                                                      eidx, ew, cnt, col_t, eid_t, w_t,
                                                      sector, active, packed, N, E, cap, nb);
    main_kernel<<<N, 256, 0, stream>>>(s_dst, s_src, packed, active, lam, cnt,
                                       col_t, eid_t, w_t, out, N, cap);
}

// Round 6
// 196.011 us; speedup vs baseline: 1.3468x; 1.3468x over previous
//
#include <hip/hip_runtime.h>
#include <math.h>

#define H_DIM 256
#define HEADS 4
#define HD 64
#define TOPK 15
#define NSLOPE 0.2
#define EDGE_CAP_MAX 128
#define CAND_CAP 256

// prep1: 16 blocks. All blocks zero cnt (16 KB); blocks 0..7 also compute wa
// for (head = b>>1, side = b&1).
__global__ __launch_bounds__(256) void prep1_kernel(const float* __restrict__ W,
                                                    const float* __restrict__ att,
                                                    double* __restrict__ wa_dst,
                                                    double* __restrict__ wa_src,
                                                    int* __restrict__ cnt) {
    const int b = blockIdx.x;
    cnt[b * 256 + threadIdx.x] = 0;
    if (b < 2 * HEADS) {
        const int k = threadIdx.x;
        const int h = b >> 1;
        const int side = b & 1;
        double a = 0.0;
        for (int d = 0; d < HD; ++d)
            a += (double)W[(h * HD + d) * H_DIM + k] * (double)att[h * 2 * HD + side * HD + d];
        (side ? wa_src : wa_dst)[h * H_DIM + k] = a;
    }
}

// prep2: fused independent stages, partitioned by blockIdx:
//   [0, 1024)            s-compute: one wave per row (4 rows/block)
//   [1024, 1024+nb)      edge-table build (thread per edge)
//   [1024+nb, +4096)     mask pack: one block per row, vectorized bit-transpose
__global__ __launch_bounds__(256) void prep2_kernel(
    const float* __restrict__ emb, const double* __restrict__ wa_dst,
    const double* __restrict__ wa_src, double* __restrict__ s_dst,
    double* __restrict__ s_src, const int* __restrict__ eidx,
    const float* __restrict__ ew, int* __restrict__ cnt, int* __restrict__ col_t,
    int* __restrict__ eid_t, float* __restrict__ w_t,
    const int* __restrict__ sector_mask, const int* __restrict__ active,
    unsigned short* __restrict__ packed, int N, int E, int cap, int nb) {
    const int b = blockIdx.x;
    const int tid = threadIdx.x;

    if (b < 1024) {
        // ---- s-compute ----
        const int lane = tid & 63;
        const int wid = tid >> 6;
        const int i = b * 4 + wid;
        double e[4];
#pragma unroll
        for (int m = 0; m < 4; ++m) e[m] = (double)emb[(size_t)i * H_DIM + lane + 64 * m];
        double acc[8];
#pragma unroll
        for (int c = 0; c < 8; ++c) {
            const double* wa = (c & 1) ? wa_src : wa_dst;
            const int h = c >> 1;
            double a = 0.0;
#pragma unroll
            for (int m = 0; m < 4; ++m) a += e[m] * wa[h * H_DIM + lane + 64 * m];
            acc[c] = a;
        }
#pragma unroll
        for (int m = 1; m < 64; m <<= 1) {
#pragma unroll
            for (int c = 0; c < 8; ++c) acc[c] += __shfl_xor(acc[c], m, 64);
        }
        if (lane == 0) {
#pragma unroll
            for (int c = 0; c < 8; ++c) {
                double* dst = (c & 1) ? s_src : s_dst;
                dst[i * HEADS + (c >> 1)] = acc[c];
            }
        }
    } else if (b < 1024 + nb) {
        // ---- edge-table build (slot order nondeterministic; dedup is by max
        // edge id, which is order-independent) ----
        const int e = (b - 1024) * 256 + tid;
        if (e < E) {
            const int r = eidx[e];
            const int c = eidx[E + e];
            const int s = atomicAdd(&cnt[r], 1);
            if (s < cap) {
                col_t[r * cap + s] = c;
                eid_t[r * cap + s] = e;
                w_t[r * cap + s] = ew[e];
            }
        }
    } else {
        // ---- mask pack: block per row; conflict-free bit-transpose ----
        // column j = rr*1024 + w*256 + 4*lane + c  ->  word (4*lane+c), bit (4*rr+w)
        const int r = b - 1024 - nb;
        const int lane = tid & 63;
        const int w = tid >> 6;
        const int* mrow = sector_mask + (size_t)r * N;
        __shared__ unsigned short lds[1024];
        unsigned short b0 = 0, b1 = 0, b2 = 0, b3 = 0;
#pragma unroll
        for (int rr = 0; rr < 4; ++rr) {
            const int j = rr * 1024 + w * 256 + 4 * lane;
            const int4 m = *(const int4*)(mrow + j);
            const int4 a = *(const int4*)(active + j);
            const unsigned short bit = (unsigned short)(1u << (4 * rr + w));
            if (m.x && a.x) b0 |= bit;
            if (m.y && a.y) b1 |= bit;
            if (m.z && a.z) b2 |= bit;
            if (m.w && a.w) b3 |= bit;
        }
        ushort4 st;
        st.x = b0; st.y = b1; st.z = b2; st.w = b3;
        *(ushort4*)(lds + w * 256 + 4 * lane) = st;
        __syncthreads();
        packed[r * 256 + tid] =
            (unsigned short)(lds[tid] | lds[256 + tid] | lds[512 + tid] | lds[768 + tid]);
    }
}

#define FOR16(OP) OP(0) OP(1) OP(2) OP(3) OP(4) OP(5) OP(6) OP(7) \
                  OP(8) OP(9) OP(10) OP(11) OP(12) OP(13) OP(14) OP(15)

// One block per row. 16 fp64 scores in named registers (thread owns columns
// j = tid + 256k). Selection: fp32 keys -> per-wave ballot binary-search
// threshold -> candidate filter -> exact fp64 rank-by-counting.
__global__ __launch_bounds__(256) void main_kernel(
    const double* __restrict__ s_dst, const double* __restrict__ s_src,
    const unsigned short* __restrict__ packed, const int* __restrict__ active,
    const float* __restrict__ lam_p, const int* __restrict__ cnt,
    const int* __restrict__ col_t, const int* __restrict__ eid_t,
    const float* __restrict__ w_t, float* __restrict__ out, int N, int cap) {
    const int i = blockIdx.x;
    const int tid = threadIdx.x;
    const int lane = tid & 63;
    const int wid = tid >> 6;

    __shared__ int ec[EDGE_CAP_MAX];
    __shared__ int ee[EDGE_CAP_MAX];
    __shared__ float ewl[EDGE_CAP_MAX];
    __shared__ int wcol[EDGE_CAP_MAX];
    __shared__ double wadd[EDGE_CAP_MAX];
    __shared__ unsigned int wth[4];
    __shared__ double cand_v[CAND_CAP];
    __shared__ int cand_i[CAND_CAP];
    __shared__ int cand_cnt, wcnt;
    __shared__ double sorted_v[TOPK];
    __shared__ int sorted_i[TOPK];
    __shared__ double exps[TOPK];

    if (tid == 0) { cand_cnt = 0; wcnt = 0; }

    // Stage this row's edge slice into LDS
    int deg = cnt[i];
    if (deg > cap) deg = cap;
    for (int p = tid; p < deg; p += 256) {
        ec[p] = col_t[i * cap + p];
        ee[p] = eid_t[i * cap + p];
        ewl[p] = w_t[i * cap + p];
    }

    const double sd0 = s_dst[i * 4 + 0];
    const double sd1 = s_dst[i * 4 + 1];
    const double sd2 = s_dst[i * 4 + 2];
    const double sd3 = s_dst[i * 4 + 3];
    const bool ai = (active[i] != 0);
    const double lam = (double)lam_p[0];
    const double4* __restrict__ s_src4 = (const double4*)s_src;
    const unsigned int pm = ai ? (unsigned int)packed[i * 256 + tid] : 0u;

    // Phase 1: scores into 16 named fp64 registers
    double v0, v1, v2, v3, v4, v5, v6, v7, v8, v9, v10, v11, v12, v13, v14, v15;
#define INIT_SLOT(K) { \
    const bool m = (pm >> K) & 1u; \
    const double4 sv = s_src4[tid + (K << 8)]; \
    double x0 = sd0 + sv.x, x1 = sd1 + sv.y, x2 = sd2 + sv.z, x3 = sd3 + sv.w; \
    x0 = (x0 < 0.0) ? NSLOPE * x0 : x0; \
    x1 = (x1 < 0.0) ? NSLOPE * x1 : x1; \
    x2 = (x2 < 0.0) ? NSLOPE * x2 : x2; \
    x3 = (x3 < 0.0) ? NSLOPE * x3 : x3; \
    v##K = m ? (0.25 * (x0 + x1 + x2 + x3)) : -INFINITY; }
    FOR16(INIT_SLOT)
#undef INIT_SLOT

    __syncthreads();  // edges + counters visible

    // Phase 2a: parallel dedup (last-write-wins by edge id), thread-per-edge
    if (tid < deg) {
        const int c = ec[tid];
        const int eid = ee[tid];
        bool win = true;
        for (int q = 0; q < deg; ++q)
            if (ec[q] == c && ee[q] > eid) win = false;
        if (win) {
            int p = atomicAdd(&wcnt, 1);
            wcol[p] = c;
            wadd[p] = lam * (double)ewl[tid];
        }
    }
    __syncthreads();

    // Phase 2b: owners apply winner adds (-inf + add stays -inf)
    const int nw = wcnt;
    for (int w = 0; w < nw; ++w) {
        const int c = wcol[w];
        if ((c & 255) == tid) {
            const double add = wadd[w];
            const int kk = c >> 8;
#define ADD_SLOT(K) if (kk == K) v##K += add;
            FOR16(ADD_SLOT)
#undef ADD_SLOT
        }
    }

    // Phase 3a: fp32 monotone keys + per-thread local max
    unsigned int k0, k1, k2, k3, k4, k5, k6, k7, k8, k9, k10, k11, k12, k13, k14, k15;
#define KEY_SLOT(K) { const float f = (float)v##K; const unsigned u = __float_as_uint(f); \
    k##K = u ^ ((unsigned)((int)u >> 31) | 0x80000000u); }
    FOR16(KEY_SLOT)
#undef KEY_SLOT
    unsigned int lmax = k0;
#define LMAX(K) if (k##K > lmax) lmax = k##K;
    FOR16(LMAX)
#undef LMAX

    // Phase 3b: per-wave 15th-largest lane-max via ballot binary search
    // (valid lower bound on the row's true 15th value)
    unsigned int th = 0;
    for (int b = 31; b >= 0; --b) {
        const unsigned int trial = th | (1u << b);
        unsigned long long m = __ballot(lmax >= trial);
        if (__popcll(m) >= TOPK) th = trial;
    }
    if (lane == 0) wth[wid] = th;
    __syncthreads();
    th = wth[0];
    if (wth[1] > th) th = wth[1];
    if (wth[2] > th) th = wth[2];
    if (wth[3] > th) th = wth[3];

    // Phase 3c: candidate filter (superset of true top-15 by monotonicity)
#define FILT(K) if (k##K >= th) { int p = atomicAdd(&cand_cnt, 1); \
    if (p < CAND_CAP) { cand_v[p] = v##K; cand_i[p] = tid + (K << 8); } }
    FOR16(FILT)
#undef FILT
    __syncthreads();

    // Phase 4: exact fp64 rank-by-counting among C candidates (unique ranks)
    int C = cand_cnt;
    if (C > CAND_CAP) C = CAND_CAP;
    if (tid < C) {
        const double mv = cand_v[tid];
        const int mi = cand_i[tid];
        int rank = 0;
        for (int q = 0; q < C; ++q) {
            const double qv = cand_v[q];
            const int qi = cand_i[q];
            rank += ((qv > mv) || (qv == mv && qi < mi)) ? 1 : 0;
        }
        if (rank < TOPK) { sorted_v[rank] = mv; sorted_i[rank] = mi; }
    }
    __syncthreads();

    // Phase 5: softmax + store
    if (tid < TOPK) exps[tid] = exp(sorted_v[tid] - sorted_v[0]);
    __syncthreads();
    if (tid < TOPK) {
        double s = 0.0;
        for (int t = 0; t < TOPK; ++t) s += exps[t];
        const int NK = N * TOPK;
        const int base = i * TOPK + tid;
        out[base] = (float)sorted_i[tid];      // edge_index row 0: topk column idx
        out[NK + base] = (float)i;             // edge_index row 1: source row
        out[2 * NK + base] = (float)(exps[tid] / s);  // edge_weight (softmax)
    }
}

extern "C" void kernel_launch(void* const* d_in, const int* in_sizes, int n_in,
                              void* d_out, int out_size, void* d_ws, size_t ws_size,
                              hipStream_t stream) {
    const float* emb    = (const float*)d_in[0];
    const float* W      = (const float*)d_in[1];
    const float* att    = (const float*)d_in[2];
    const float* lam    = (const float*)d_in[3];
    const int*   sector = (const int*)d_in[4];
    const int*   active = (const int*)d_in[5];
    const int*   eidx   = (const int*)d_in[6];
    const float* ew     = (const float*)d_in[7];
    float* out = (float*)d_out;

    const int N = in_sizes[5];      // 4096
    const int E = in_sizes[6] / 2;  // 131072

    // workspace layout
    double* wa_dst = (double*)d_ws;                       // 1024 dbl
    double* wa_src = wa_dst + HEADS * H_DIM;              // 1024 dbl
    double* s_dst  = wa_src + HEADS * H_DIM;              // N*4 dbl
    double* s_src  = s_dst + (size_t)N * HEADS;           // N*4 dbl
    int* cnt       = (int*)(s_src + (size_t)N * HEADS);   // N int
    unsigned short* packed = (unsigned short*)(cnt + N);  // N*256 ushort (2 MB)
    int* col_t     = (int*)(packed + (size_t)N * 256);

    size_t used = (size_t)(2 * HEADS * H_DIM + 2 * (size_t)N * HEADS) * 8
                  + (size_t)N * 4 + (size_t)N * 512 + 256;
    size_t rem = (ws_size > used) ? (ws_size - used) : 0;
    int cap = (int)(rem / ((size_t)N * 12));
    if (cap > EDGE_CAP_MAX) cap = EDGE_CAP_MAX;
    if (cap < 16) cap = 16;

    int* eid_t = col_t + (size_t)N * cap;
    float* w_t = (float*)(eid_t + (size_t)N * cap);

    const int nb = (E + 255) / 256;  // build blocks (512)

    prep1_kernel<<<16, 256, 0, stream>>>(W, att, wa_dst, wa_src, cnt);
    prep2_kernel<<<1024 + nb + N, 256, 0, stream>>>(emb, wa_dst, wa_src, s_dst, s_src,
                                                    eidx, ew, cnt, col_t, eid_t, w_t,
                                                    sector, active, packed, N, E, cap, nb);
    main_kernel<<<N, 256, 0, stream>>>(s_dst, s_src, packed, active, lam, cnt,
                                       col_t, eid_t, w_t, out, N, cap);
}

// Round 7
// 189.566 us; speedup vs baseline: 1.3926x; 1.0340x over previous
//
#include <hip/hip_runtime.h>
#include <math.h>

#define H_DIM 256
#define HEADS 4
#define HD 64
#define TOPK 15
#define NSLOPE 0.2
#define EDGE_CAP_MAX 128
#define CAND_CAP 256

// prep1: 16 blocks. All blocks zero cnt (16 KB); blocks 0..7 compute wa for
// (head = b>>1, side = b&1); block 15 packs active[] into a 4096-bit mask.
__global__ __launch_bounds__(256) void prep1_kernel(const float* __restrict__ W,
                                                    const float* __restrict__ att,
                                                    double* __restrict__ wa_dst,
                                                    double* __restrict__ wa_src,
                                                    int* __restrict__ cnt,
                                                    unsigned int* __restrict__ abits,
                                                    const int* __restrict__ active) {
    const int b = blockIdx.x;
    cnt[b * 256 + threadIdx.x] = 0;
    if (b < 2 * HEADS) {
        const int k = threadIdx.x;
        const int h = b >> 1;
        const int side = b & 1;
        double a = 0.0;
        for (int d = 0; d < HD; ++d)
            a += (double)W[(h * HD + d) * H_DIM + k] * (double)att[h * 2 * HD + side * HD + d];
        (side ? wa_src : wa_dst)[h * H_DIM + k] = a;
    } else if (b == 15 && threadIdx.x < 128) {
        const int* ap = active + threadIdx.x * 32;
        unsigned int wv = 0;
        for (int t = 0; t < 32; ++t)
            if (ap[t]) wv |= 1u << t;
        abits[threadIdx.x] = wv;
    }
}

// prep2: fused independent stages, partitioned by blockIdx:
//   [0, 1024)        s-compute: one wave per row (4 rows/block)
//   [1024, 1024+nb)  edge-table build (thread per edge)
__global__ __launch_bounds__(256) void prep2_kernel(
    const float* __restrict__ emb, const double* __restrict__ wa_dst,
    const double* __restrict__ wa_src, double* __restrict__ s_dst,
    double* __restrict__ s_src, const int* __restrict__ eidx,
    const float* __restrict__ ew, int* __restrict__ cnt, int* __restrict__ col_t,
    int* __restrict__ eid_t, float* __restrict__ w_t, int N, int E, int cap) {
    const int b = blockIdx.x;
    const int tid = threadIdx.x;

    if (b < 1024) {
        // ---- s-compute ----
        const int lane = tid & 63;
        const int wid = tid >> 6;
        const int i = b * 4 + wid;
        double e[4];
#pragma unroll
        for (int m = 0; m < 4; ++m) e[m] = (double)emb[(size_t)i * H_DIM + lane + 64 * m];
        double acc[8];
#pragma unroll
        for (int c = 0; c < 8; ++c) {
            const double* wa = (c & 1) ? wa_src : wa_dst;
            const int h = c >> 1;
            double a = 0.0;
#pragma unroll
            for (int m = 0; m < 4; ++m) a += e[m] * wa[h * H_DIM + lane + 64 * m];
            acc[c] = a;
        }
#pragma unroll
        for (int m = 1; m < 64; m <<= 1) {
#pragma unroll
            for (int c = 0; c < 8; ++c) acc[c] += __shfl_xor(acc[c], m, 64);
        }
        if (lane == 0) {
#pragma unroll
            for (int c = 0; c < 8; ++c) {
                double* dst = (c & 1) ? s_src : s_dst;
                dst[i * HEADS + (c >> 1)] = acc[c];
            }
        }
    } else {
        // ---- edge-table build (slot order nondeterministic; dedup is by max
        // edge id, which is order-independent) ----
        const int e = (b - 1024) * 256 + tid;
        if (e < E) {
            const int r = eidx[e];
            const int c = eidx[E + e];
            const int s = atomicAdd(&cnt[r], 1);
            if (s < cap) {
                col_t[r * cap + s] = c;
                eid_t[r * cap + s] = e;
                w_t[r * cap + s] = ew[e];
            }
        }
    }
}

#define FOR16(OP) OP(0) OP(1) OP(2) OP(3) OP(4) OP(5) OP(6) OP(7) \
                  OP(8) OP(9) OP(10) OP(11) OP(12) OP(13) OP(14) OP(15)

// One block per row. Coalesced mask-row read + 512 B LDS bit-transpose; 16
// fp64 scores in named registers (thread owns columns j = tid + 256k).
// Selection: fp32 keys -> per-wave ballot binary-search threshold ->
// candidate filter -> exact fp64 rank-by-counting.
__global__ __launch_bounds__(256) void main_kernel(
    const double* __restrict__ s_dst, const double* __restrict__ s_src,
    const int* __restrict__ sector_mask, const unsigned short* __restrict__ abits16,
    const int* __restrict__ active, const float* __restrict__ lam_p,
    const int* __restrict__ cnt, const int* __restrict__ col_t,
    const int* __restrict__ eid_t, const float* __restrict__ w_t,
    float* __restrict__ out, int N, int cap) {
    const int i = blockIdx.x;
    const int tid = threadIdx.x;
    const int lane = tid & 63;
    const int wid = tid >> 6;

    __shared__ int ec[EDGE_CAP_MAX];
    __shared__ int ee[EDGE_CAP_MAX];
    __shared__ float ewl[EDGE_CAP_MAX];
    __shared__ int wcol[EDGE_CAP_MAX];
    __shared__ double wadd[EDGE_CAP_MAX];
    __shared__ unsigned short lds16[256];
    __shared__ unsigned int wth[4];
    __shared__ double cand_v[CAND_CAP];
    __shared__ int cand_i[CAND_CAP];
    __shared__ int cand_cnt, wcnt;
    __shared__ double sorted_v[TOPK];
    __shared__ int sorted_i[TOPK];
    __shared__ double exps[TOPK];

    if (tid == 0) { cand_cnt = 0; wcnt = 0; }

    // Stage this row's edge slice into LDS
    int deg = cnt[i];
    if (deg > cap) deg = cap;
    for (int p = tid; p < deg; p += 256) {
        ec[p] = col_t[i * cap + p];
        ee[p] = eid_t[i * cap + p];
        ewl[p] = w_t[i * cap + p];
    }

    // Coalesced mask-row read: thread t loads columns 16t..16t+15 (64 B
    // contiguous), ANDs with the active ushort slice (bit c <-> col 16t+c),
    // stores one 16-bit word. Mapping: col j=16t+c -> LDS word 16*(t&15)+c,
    // bit position t>>4.
    const int* mrow = sector_mask + (size_t)i * N;
    const unsigned int act_us = (unsigned int)abits16[tid];
    const int4 m0 = *(const int4*)(mrow + 16 * tid);
    const int4 m1 = *(const int4*)(mrow + 16 * tid + 4);
    const int4 m2 = *(const int4*)(mrow + 16 * tid + 8);
    const int4 m3 = *(const int4*)(mrow + 16 * tid + 12);
    unsigned int pb = 0;
#define PB(C, VAL) if ((VAL) != 0) pb |= (1u << (C));
    PB(0, m0.x)  PB(1, m0.y)  PB(2, m0.z)  PB(3, m0.w)
    PB(4, m1.x)  PB(5, m1.y)  PB(6, m1.z)  PB(7, m1.w)
    PB(8, m2.x)  PB(9, m2.y)  PB(10, m2.z) PB(11, m2.w)
    PB(12, m3.x) PB(13, m3.y) PB(14, m3.z) PB(15, m3.w)
#undef PB
    pb &= act_us;
    lds16[tid] = (unsigned short)pb;

    const double sd0 = s_dst[i * 4 + 0];
    const double sd1 = s_dst[i * 4 + 1];
    const double sd2 = s_dst[i * 4 + 2];
    const double sd3 = s_dst[i * 4 + 3];
    const bool ai = (active[i] != 0);
    const double lam = (double)lam_p[0];
    const double4* __restrict__ s_src4 = (const double4*)s_src;

    __syncthreads();  // edges + lds16 + counters visible

    // Gather: word w=tid needs bit position q from loader t=16q+(w>>4),
    // taking bit (w&15) of its word (stored at lds16[t]).
    unsigned int pm = 0;
#pragma unroll
    for (int q = 0; q < 16; ++q)
        pm |= ((unsigned int)(lds16[(q << 4) | (tid >> 4)] >> (tid & 15)) & 1u) << q;
    if (!ai) pm = 0;

    // Phase 1: scores into 16 named fp64 registers
    double v0, v1, v2, v3, v4, v5, v6, v7, v8, v9, v10, v11, v12, v13, v14, v15;
#define INIT_SLOT(K) { \
    const bool m = (pm >> K) & 1u; \
    const double4 sv = s_src4[tid + (K << 8)]; \
    double x0 = sd0 + sv.x, x1 = sd1 + sv.y, x2 = sd2 + sv.z, x3 = sd3 + sv.w; \
    x0 = (x0 < 0.0) ? NSLOPE * x0 : x0; \
    x1 = (x1 < 0.0) ? NSLOPE * x1 : x1; \
    x2 = (x2 < 0.0) ? NSLOPE * x2 : x2; \
    x3 = (x3 < 0.0) ? NSLOPE * x3 : x3; \
    v##K = m ? (0.25 * (x0 + x1 + x2 + x3)) : -INFINITY; }
    FOR16(INIT_SLOT)
#undef INIT_SLOT

    // Phase 2a: parallel dedup (last-write-wins by edge id), thread-per-edge
    if (tid < deg) {
        const int c = ec[tid];
        const int eid = ee[tid];
        bool win = true;
        for (int q = 0; q < deg; ++q)
            if (ec[q] == c && ee[q] > eid) win = false;
        if (win) {
            int p = atomicAdd(&wcnt, 1);
            wcol[p] = c;
            wadd[p] = lam * (double)ewl[tid];
        }
    }
    __syncthreads();

    // Phase 2b: owners apply winner adds (-inf + add stays -inf)
    const int nw = wcnt;
    for (int w = 0; w < nw; ++w) {
        const int c = wcol[w];
        if ((c & 255) == tid) {
            const double add = wadd[w];
            const int kk = c >> 8;
#define ADD_SLOT(K) if (kk == K) v##K += add;
            FOR16(ADD_SLOT)
#undef ADD_SLOT
        }
    }

    // Phase 3a: fp32 monotone keys + per-thread local max
    unsigned int k0, k1, k2, k3, k4, k5, k6, k7, k8, k9, k10, k11, k12, k13, k14, k15;
#define KEY_SLOT(K) { const float f = (float)v##K; const unsigned u = __float_as_uint(f); \
    k##K = u ^ ((unsigned)((int)u >> 31) | 0x80000000u); }
    FOR16(KEY_SLOT)
#undef KEY_SLOT
    unsigned int lmax = k0;
#define LMAX(K) if (k##K > lmax) lmax = k##K;
    FOR16(LMAX)
#undef LMAX

    // Phase 3b: per-wave 15th-largest lane-max via ballot binary search
    // (valid lower bound on the row's true 15th value)
    unsigned int th = 0;
    for (int b = 31; b >= 0; --b) {
        const unsigned int trial = th | (1u << b);
        unsigned long long m = __ballot(lmax >= trial);
        if (__popcll(m) >= TOPK) th = trial;
    }
    if (lane == 0) wth[wid] = th;
    __syncthreads();
    th = wth[0];
    if (wth[1] > th) th = wth[1];
    if (wth[2] > th) th = wth[2];
    if (wth[3] > th) th = wth[3];

    // Phase 3c: candidate filter (superset of true top-15 by monotonicity)
#define FILT(K) if (k##K >= th) { int p = atomicAdd(&cand_cnt, 1); \
    if (p < CAND_CAP) { cand_v[p] = v##K; cand_i[p] = tid + (K << 8); } }
    FOR16(FILT)
#undef FILT
    __syncthreads();

    // Phase 4: exact fp64 rank-by-counting among C candidates (unique ranks)
    int C = cand_cnt;
    if (C > CAND_CAP) C = CAND_CAP;
    if (tid < C) {
        const double mv = cand_v[tid];
        const int mi = cand_i[tid];
        int rank = 0;
        for (int q = 0; q < C; ++q) {
            const double qv = cand_v[q];
            const int qi = cand_i[q];
            rank += ((qv > mv) || (qv == mv && qi < mi)) ? 1 : 0;
        }
        if (rank < TOPK) { sorted_v[rank] = mv; sorted_i[rank] = mi; }
    }
    __syncthreads();

    // Phase 5: softmax + store
    if (tid < TOPK) exps[tid] = exp(sorted_v[tid] - sorted_v[0]);
    __syncthreads();
    if (tid < TOPK) {
        double s = 0.0;
        for (int t = 0; t < TOPK; ++t) s += exps[t];
        const int NK = N * TOPK;
        const int base = i * TOPK + tid;
        out[base] = (float)sorted_i[tid];      // edge_index row 0: topk column idx
        out[NK + base] = (float)i;             // edge_index row 1: source row
        out[2 * NK + base] = (float)(exps[tid] / s);  // edge_weight (softmax)
    }
}

extern "C" void kernel_launch(void* const* d_in, const int* in_sizes, int n_in,
                              void* d_out, int out_size, void* d_ws, size_t ws_size,
                              hipStream_t stream) {
    const float* emb    = (const float*)d_in[0];
    const float* W      = (const float*)d_in[1];
    const float* att    = (const float*)d_in[2];
    const float* lam    = (const float*)d_in[3];
    const int*   sector = (const int*)d_in[4];
    const int*   active = (const int*)d_in[5];
    const int*   eidx   = (const int*)d_in[6];
    const float* ew     = (const float*)d_in[7];
    float* out = (float*)d_out;

    const int N = in_sizes[5];      // 4096
    const int E = in_sizes[6] / 2;  // 131072

    // workspace layout
    double* wa_dst = (double*)d_ws;                       // 1024 dbl
    double* wa_src = wa_dst + HEADS * H_DIM;              // 1024 dbl
    double* s_dst  = wa_src + HEADS * H_DIM;              // N*4 dbl
    double* s_src  = s_dst + (size_t)N * HEADS;           // N*4 dbl
    int* cnt       = (int*)(s_src + (size_t)N * HEADS);   // N int
    unsigned int* abits = (unsigned int*)(cnt + N);       // N/32 uint (128)
    int* col_t     = (int*)(abits + N / 32);

    size_t used = (size_t)(2 * HEADS * H_DIM + 2 * (size_t)N * HEADS) * 8
                  + (size_t)N * 4 + (size_t)(N / 32) * 4 + 256;
    size_t rem = (ws_size > used) ? (ws_size - used) : 0;
    int cap = (int)(rem / ((size_t)N * 12));
    if (cap > EDGE_CAP_MAX) cap = EDGE_CAP_MAX;
    if (cap < 16) cap = 16;

    int* eid_t = col_t + (size_t)N * cap;
    float* w_t = (float*)(eid_t + (size_t)N * cap);

    const int nb = (E + 255) / 256;  // build blocks (512)

    prep1_kernel<<<16, 256, 0, stream>>>(W, att, wa_dst, wa_src, cnt, abits, active);
    prep2_kernel<<<1024 + nb, 256, 0, stream>>>(emb, wa_dst, wa_src, s_dst, s_src,
                                                eidx, ew, cnt, col_t, eid_t, w_t, N, E, cap);
    main_kernel<<<N, 256, 0, stream>>>(s_dst, s_src, sector, (const unsigned short*)abits,
                                       active, lam, cnt, col_t, eid_t, w_t, out, N, cap);
}

// Round 9
// 182.267 us; speedup vs baseline: 1.4483x; 1.0400x over previous
//
#include <hip/hip_runtime.h>
#include <math.h>

#define H_DIM 256
#define HEADS 4
#define HD 64
#define TOPK 15
#define NSLOPE 0.2
#define NSLOPEF 0.2f
#define EDGE_CAP_MAX 128
#define CAND_CAP 256

// prep1: 8 blocks, wa only. wa[(h,side)][k] = sum_d W[(h*64+d)*256+k]*att[h*128+side*64+d]
__global__ __launch_bounds__(256) void prep1_kernel(const float* __restrict__ W,
                                                    const float* __restrict__ att,
                                                    double* __restrict__ wa_dst,
                                                    double* __restrict__ wa_src) {
    const int k = threadIdx.x;
    const int h = blockIdx.x >> 1;
    const int side = blockIdx.x & 1;
    double a = 0.0;
    for (int d = 0; d < HD; ++d)
        a += (double)W[(h * HD + d) * H_DIM + k] * (double)att[h * 2 * HD + side * HD + d];
    (side ? wa_src : wa_dst)[h * H_DIM + k] = a;
}

// prep2: fused independent stages, partitioned by blockIdx:
//   [0, 1024)        s-compute: one wave per row (writes fp64 + fp32 copies)
//   [1024, 1024+nb)  edge-table build (thread per edge)
//   1024+nb          active[] -> 4096-bit abits pack
__global__ __launch_bounds__(256) void prep2_kernel(
    const float* __restrict__ emb, const double* __restrict__ wa_dst,
    const double* __restrict__ wa_src, double* __restrict__ s_dst,
    double* __restrict__ s_src, float* __restrict__ s_dst_f,
    float* __restrict__ s_src_f, const int* __restrict__ eidx,
    const float* __restrict__ ew, int* __restrict__ cnt, int* __restrict__ col_t,
    int* __restrict__ eid_t, float* __restrict__ w_t,
    const int* __restrict__ active, unsigned int* __restrict__ abits,
    int N, int E, int cap, int nb) {
    const int b = blockIdx.x;
    const int tid = threadIdx.x;

    if (b < 1024) {
        // ---- s-compute ----
        const int lane = tid & 63;
        const int wid = tid >> 6;
        const int i = b * 4 + wid;
        double e[4];
#pragma unroll
        for (int m = 0; m < 4; ++m) e[m] = (double)emb[(size_t)i * H_DIM + lane + 64 * m];
        double acc[8];
#pragma unroll
        for (int c = 0; c < 8; ++c) {
            const double* wa = (c & 1) ? wa_src : wa_dst;
            const int h = c >> 1;
            double a = 0.0;
#pragma unroll
            for (int m = 0; m < 4; ++m) a += e[m] * wa[h * H_DIM + lane + 64 * m];
            acc[c] = a;
        }
#pragma unroll
        for (int m = 1; m < 64; m <<= 1) {
#pragma unroll
            for (int c = 0; c < 8; ++c) acc[c] += __shfl_xor(acc[c], m, 64);
        }
        if (lane == 0) {
#pragma unroll
            for (int c = 0; c < 8; ++c) {
                const int h = c >> 1;
                if (c & 1) {
                    s_src[i * HEADS + h] = acc[c];
                    s_src_f[i * HEADS + h] = (float)acc[c];
                } else {
                    s_dst[i * HEADS + h] = acc[c];
                    s_dst_f[i * HEADS + h] = (float)acc[c];
                }
            }
        }
    } else if (b < 1024 + nb) {
        // ---- edge-table build (slot order nondeterministic; dedup is by max
        // edge id, which is order-independent) ----
        const int e = (b - 1024) * 256 + tid;
        if (e < E) {
            const int r = eidx[e];
            const int c = eidx[E + e];
            const int s = atomicAdd(&cnt[r], 1);
            if (s < cap) {
                col_t[r * cap + s] = c;
                eid_t[r * cap + s] = e;
                w_t[r * cap + s] = ew[e];
            }
        }
    } else if (tid < 128) {
        // ---- abits pack ----
        const int* ap = active + tid * 32;
        unsigned int wv = 0;
        for (int t = 0; t < 32; ++t)
            if (ap[t]) wv |= 1u << t;
        abits[tid] = wv;
    }
}

#define FOR16(OP) OP(0) OP(1) OP(2) OP(3) OP(4) OP(5) OP(6) OP(7) \
                  OP(8) OP(9) OP(10) OP(11) OP(12) OP(13) OP(14) OP(15)

// One block per row. Coalesced mask-row read + 512 B LDS bit-transpose.
// Selection runs in fp32 (16 named regs); the ballot threshold is relaxed by
// 256 ulp so the candidate set provably contains the fp64 top-15; candidates
// are then re-scored EXACTLY in fp64 (same expression order as R7) and ranked
// by (fp64 value, index) -> output bit-identical to the all-fp64 kernel.
__global__ __launch_bounds__(256) void main_kernel(
    const double* __restrict__ s_dst, const double* __restrict__ s_src,
    const float* __restrict__ s_dst_f, const float* __restrict__ s_src_f,
    const int* __restrict__ sector_mask, const unsigned short* __restrict__ abits16,
    const int* __restrict__ active, const float* __restrict__ lam_p,
    const int* __restrict__ cnt, const int* __restrict__ col_t,
    const int* __restrict__ eid_t, const float* __restrict__ w_t,
    float* __restrict__ out, int N, int cap) {
    const int i = blockIdx.x;
    const int tid = threadIdx.x;
    const int lane = tid & 63;
    const int wid = tid >> 6;

    __shared__ int ec[EDGE_CAP_MAX];
    __shared__ int ee[EDGE_CAP_MAX];
    __shared__ float ewl[EDGE_CAP_MAX];
    __shared__ int wcol[EDGE_CAP_MAX];
    __shared__ double wadd[EDGE_CAP_MAX];   // fp64 winner add (exact re-rank)
    __shared__ unsigned short lds16[256];
    __shared__ unsigned int wth[4];
    __shared__ double cand_v[CAND_CAP];
    __shared__ int cand_i[CAND_CAP];
    __shared__ int cand_cnt, wcnt;
    __shared__ double sorted_v[TOPK];
    __shared__ int sorted_i[TOPK];
    __shared__ double exps[TOPK];

    if (tid == 0) { cand_cnt = 0; wcnt = 0; }

    // Stage this row's edge slice into LDS
    int deg = cnt[i];
    if (deg > cap) deg = cap;
    for (int p = tid; p < deg; p += 256) {
        ec[p] = col_t[i * cap + p];
        ee[p] = eid_t[i * cap + p];
        ewl[p] = w_t[i * cap + p];
    }

    // Coalesced mask-row read (64 B/thread) + AND with active ushort slice.
    const int* mrow = sector_mask + (size_t)i * N;
    const unsigned int act_us = (unsigned int)abits16[tid];
    const int4 m0 = *(const int4*)(mrow + 16 * tid);
    const int4 m1 = *(const int4*)(mrow + 16 * tid + 4);
    const int4 m2 = *(const int4*)(mrow + 16 * tid + 8);
    const int4 m3 = *(const int4*)(mrow + 16 * tid + 12);
    unsigned int pb = 0;
#define PB(C, VAL) if ((VAL) != 0) pb |= (1u << (C));
    PB(0, m0.x)  PB(1, m0.y)  PB(2, m0.z)  PB(3, m0.w)
    PB(4, m1.x)  PB(5, m1.y)  PB(6, m1.z)  PB(7, m1.w)
    PB(8, m2.x)  PB(9, m2.y)  PB(10, m2.z) PB(11, m2.w)
    PB(12, m3.x) PB(13, m3.y) PB(14, m3.z) PB(15, m3.w)
#undef PB
    pb &= act_us;
    lds16[tid] = (unsigned short)pb;

    // fp32 sd for selection; fp64 sd for exact re-rank
    const float sdf0 = s_dst_f[i * 4 + 0];
    const float sdf1 = s_dst_f[i * 4 + 1];
    const float sdf2 = s_dst_f[i * 4 + 2];
    const float sdf3 = s_dst_f[i * 4 + 3];
    const double sd0 = s_dst[i * 4 + 0];
    const double sd1 = s_dst[i * 4 + 1];
    const double sd2 = s_dst[i * 4 + 2];
    const double sd3 = s_dst[i * 4 + 3];
    const bool ai = (active[i] != 0);
    const double lam = (double)lam_p[0];
    const float lamf = (float)lam;
    const double4* __restrict__ s_src4 = (const double4*)s_src;
    const float4* __restrict__ s_srcf4 = (const float4*)s_src_f;

    __syncthreads();  // edges + lds16 + counters visible

    // Bit-transpose gather: word w=tid takes bit q from loader t=(q<<4)|(w>>4),
    // bit position (w&15).
    unsigned int pm = 0;
#pragma unroll
    for (int q = 0; q < 16; ++q)
        pm |= ((unsigned int)(lds16[(q << 4) | (tid >> 4)] >> (tid & 15)) & 1u) << q;
    if (!ai) pm = 0;

    // Phase 1 (fp32): scores into 16 named fp32 registers
    float f0, f1, f2, f3, f4, f5, f6, f7, f8, f9, f10, f11, f12, f13, f14, f15;
#define INIT_SLOT(K) { \
    const bool m = (pm >> K) & 1u; \
    const float4 sv = s_srcf4[tid + (K << 8)]; \
    float x0 = sdf0 + sv.x, x1 = sdf1 + sv.y, x2 = sdf2 + sv.z, x3 = sdf3 + sv.w; \
    x0 = (x0 < 0.0f) ? NSLOPEF * x0 : x0; \
    x1 = (x1 < 0.0f) ? NSLOPEF * x1 : x1; \
    x2 = (x2 < 0.0f) ? NSLOPEF * x2 : x2; \
    x3 = (x3 < 0.0f) ? NSLOPEF * x3 : x3; \
    f##K = m ? (0.25f * (x0 + x1 + x2 + x3)) : -INFINITY; }
    FOR16(INIT_SLOT)
#undef INIT_SLOT

    // Phase 2a: parallel dedup (last-write-wins by edge id), thread-per-edge
    if (tid < deg) {
        const int c = ec[tid];
        const int eid = ee[tid];
        bool win = true;
        for (int q = 0; q < deg; ++q)
            if (ec[q] == c && ee[q] > eid) win = false;
        if (win) {
            int p = atomicAdd(&wcnt, 1);
            wcol[p] = c;
            wadd[p] = lam * (double)ewl[tid];
        }
    }
    __syncthreads();

    // Phase 2b (fp32): owners apply winner adds to selection scores
    const int nw = wcnt;
    for (int w = 0; w < nw; ++w) {
        const int c = wcol[w];
        if ((c & 255) == tid) {
            const float addf = lamf * ewl[0 ? 0 : 0];  // placeholder avoided; real add below
        }
    }
    // (real 2b below — kept separate to preserve fp64 wadd for re-rank)
    for (int w = 0; w < nw; ++w) {
        const int c = wcol[w];
        if ((c & 255) == tid) {
            const float addf = (float)wadd[w];
            const int kk = c >> 8;
#define ADD_SLOT(K) if (kk == K) f##K += addf;
            FOR16(ADD_SLOT)
#undef ADD_SLOT
        }
    }

    // Phase 3a: fp32 monotone keys + per-thread local max
    unsigned int k0, k1, k2, k3, k4, k5, k6, k7, k8, k9, k10, k11, k12, k13, k14, k15;
#define KEY_SLOT(K) { const unsigned u = __float_as_uint(f##K); \
    k##K = u ^ ((unsigned)((int)u >> 31) | 0x80000000u); }
    FOR16(KEY_SLOT)
#undef KEY_SLOT
    unsigned int lmax = k0;
#define LMAX(K) if (k##K > lmax) lmax = k##K;
    FOR16(LMAX)
#undef LMAX

    // Phase 3b: per-wave 15th-largest lane-max via ballot binary search
    unsigned int th = 0;
    for (int b = 31; b >= 0; --b) {
        const unsigned int trial = th | (1u << b);
        unsigned long long m = __ballot(lmax >= trial);
        if (__popcll(m) >= TOPK) th = trial;
    }
    if (lane == 0) wth[wid] = th;
    __syncthreads();
    th = wth[0];
    if (wth[1] > th) th = wth[1];
    if (wth[2] > th) th = wth[2];
    if (wth[3] > th) th = wth[3];
    // Relax by 256 ulp: covers fp32-vs-fp64 ordering divergence near the cut.
    th = (th > 256u) ? (th - 256u) : 0u;

    // Phase 3c: candidate filter (indices only)
#define FILT(K) if (k##K >= th) { int p = atomicAdd(&cand_cnt, 1); \
    if (p < CAND_CAP) cand_i[p] = tid + (K << 8); }
    FOR16(FILT)
#undef FILT
    __syncthreads();

    // Phase 4a: exact fp64 re-score of each candidate (same expression order
    // as the all-fp64 kernel; one winner add max per column via dedup)
    int C = cand_cnt;
    if (C > CAND_CAP) C = CAND_CAP;
    if (tid < C) {
        const int j = cand_i[tid];
        const double4 sv = s_src4[j];
        double x0 = sd0 + sv.x, x1 = sd1 + sv.y, x2 = sd2 + sv.z, x3 = sd3 + sv.w;
        x0 = (x0 < 0.0) ? NSLOPE * x0 : x0;
        x1 = (x1 < 0.0) ? NSLOPE * x1 : x1;
        x2 = (x2 < 0.0) ? NSLOPE * x2 : x2;
        x3 = (x3 < 0.0) ? NSLOPE * x3 : x3;
        double v = 0.25 * (x0 + x1 + x2 + x3);
        for (int w = 0; w < nw; ++w)
            if (wcol[w] == j) v += wadd[w];
        cand_v[tid] = v;
    }
    __syncthreads();

    // Phase 4b: exact fp64 rank-by-counting among C candidates (unique ranks)
    if (tid < C) {
        const double mv = cand_v[tid];
        const int mi = cand_i[tid];
        int rank = 0;
        for (int q = 0; q < C; ++q) {
            const double qv = cand_v[q];
            const int qi = cand_i[q];
            rank += ((qv > mv) || (qv == mv && qi < mi)) ? 1 : 0;
        }
        if (rank < TOPK) { sorted_v[rank] = mv; sorted_i[rank] = mi; }
    }
    __syncthreads();

    // Phase 5: softmax + store (fp64, unchanged)
    if (tid < TOPK) exps[tid] = exp(sorted_v[tid] - sorted_v[0]);
    __syncthreads();
    if (tid < TOPK) {
        double s = 0.0;
        for (int t = 0; t < TOPK; ++t) s += exps[t];
        const int NK = N * TOPK;
        const int base = i * TOPK + tid;
        out[base] = (float)sorted_i[tid];      // edge_index row 0: topk column idx
        out[NK + base] = (float)i;             // edge_index row 1: source row
        out[2 * NK + base] = (float)(exps[tid] / s);  // edge_weight (softmax)
    }
}

extern "C" void kernel_launch(void* const* d_in, const int* in_sizes, int n_in,
                              void* d_out, int out_size, void* d_ws, size_t ws_size,
                              hipStream_t stream) {
    const float* emb    = (const float*)d_in[0];
    const float* W      = (const float*)d_in[1];
    const float* att    = (const float*)d_in[2];
    const float* lam    = (const float*)d_in[3];
    const int*   sector = (const int*)d_in[4];
    const int*   active = (const int*)d_in[5];
    const int*   eidx   = (const int*)d_in[6];
    const float* ew     = (const float*)d_in[7];
    float* out = (float*)d_out;

    const int N = in_sizes[5];      // 4096
    const int E = in_sizes[6] / 2;  // 131072

    // workspace layout
    double* wa_dst = (double*)d_ws;                       // 1024 dbl
    double* wa_src = wa_dst + HEADS * H_DIM;              // 1024 dbl
    double* s_dst  = wa_src + HEADS * H_DIM;              // N*4 dbl
    double* s_src  = s_dst + (size_t)N * HEADS;           // N*4 dbl
    float* s_dst_f = (float*)(s_src + (size_t)N * HEADS); // N*4 f32
    float* s_src_f = s_dst_f + (size_t)N * HEADS;         // N*4 f32
    int* cnt       = (int*)(s_src_f + (size_t)N * HEADS); // N int
    unsigned int* abits = (unsigned int*)(cnt + N);       // N/32 uint
    int* col_t     = (int*)(abits + N / 32);

    size_t used = (size_t)(2 * HEADS * H_DIM + 2 * (size_t)N * HEADS) * 8
                  + (size_t)(2 * (size_t)N * HEADS) * 4
                  + (size_t)N * 4 + (size_t)(N / 32) * 4 + 256;
    size_t rem = (ws_size > used) ? (ws_size - used) : 0;
    int cap = (int)(rem / ((size_t)N * 12));
    if (cap > EDGE_CAP_MAX) cap = EDGE_CAP_MAX;
    if (cap < 16) cap = 16;

    int* eid_t = col_t + (size_t)N * cap;
    float* w_t = (float*)(eid_t + (size_t)N * cap);

    const int nb = (E + 255) / 256;  // build blocks (512)

    hipMemsetAsync(cnt, 0, (size_t)N * sizeof(int), stream);
    prep1_kernel<<<2 * HEADS, 256, 0, stream>>>(W, att, wa_dst, wa_src);
    prep2_kernel<<<1024 + nb + 1, 256, 0, stream>>>(emb, wa_dst, wa_src, s_dst, s_src,
                                                    s_dst_f, s_src_f, eidx, ew, cnt,
                                                    col_t, eid_t, w_t, active, abits,
                                                    N, E, cap, nb);
    main_kernel<<<N, 256, 0, stream>>>(s_dst, s_src, s_dst_f, s_src_f, sector,
                                       (const unsigned short*)abits, active, lam, cnt,
                                       col_t, eid_t, w_t, out, N, cap);
}